// Round 3
// 595.980 us; speedup vs baseline: 1.0053x; 1.0053x over previous
//
#include <hip/hip_runtime.h>

// CoscamLoss: B=4096 rows, C=16384 cols. One block (256 thr) per row.
// loss = mean_rows [ logsumexp_j(v[j]) - v[t] ],
//   v[j] = 16 * ( j==t ? gt-0.1 : (pos[j]==1 && x[j]>=gt) ? 1.012x[j]+0.012 : x[j] )
//
// R7: R5/R6 (1024-thr blocks + reduce kernel) both died at container level
// with no counters. To split "1024-thr geometry kills the container" from
// "infra flake", this round reverts to the R4-verified geometry EXACTLY
// (256 thr/block, 16x unrolled batched loads, launch_bounds(256,3)) and
// keeps only the sink change: per-row store to d_ws (ws_size-guarded) + a
// 256-thr 1-block reduce. Fallback path == R4 byte-for-byte semantics.
//
// Numerics: shift = max(16*(gt-0.1), 40); exp2-domain throughout. Target slot
// handled by exact post-loop correction (loop treats x[t]==gt as hard when
// pos[t]==1; epilogue swaps that term for exp(16*(gt-0.1)-shift)).

#define B_ 4096
#define C_ 16384
#define LOG2E 1.44269504088896340736f

template <bool USE_ATOMIC>
__global__ __launch_bounds__(256, 3) void coscam_loss_kernel(
    const float* __restrict__ inputs,
    const int*   __restrict__ targets,
    const float* __restrict__ pos_mask,
    float*       __restrict__ sink)   // USE_ATOMIC ? &loss : partial[B_]
{
    const int row = blockIdx.x;
    const int tid = threadIdx.x;

    const float* __restrict__ rin = inputs   + (size_t)row * C_;
    const float* __restrict__ rpm = pos_mask + (size_t)row * C_;

    // Wave-uniform broadcast loads (same address across lanes -> one
    // transaction + broadcast). No LDS staging, no barrier before the loop.
    const int   t     = targets[row];
    const float gt    = rin[t];
    const float pos_t = rpm[t];        // for the epilogue correction

    const float wt      = gt - 0.1f;          // pre-scale target value
    const float out_t   = 16.0f * wt;
    const float shift   = fmaxf(out_t, 40.0f);
    const float nshift2 = -shift * LOG2E;     // exp(16w - shift) = exp2(fma(w,16log2e,nshift2))
    const float k16l2e  = 16.0f * LOG2E;

    // ---- batch ALL loads: 16 iters x (x4,p4) = 32 dwordx4 in flight ----
    float4 xs[16], ps[16];
    #pragma unroll
    for (int u = 0; u < 16; ++u) {
        const int c = u * 1024 + tid * 4;
        xs[u] = *(const float4*)(rin + c);
        ps[u] = *(const float4*)(rpm + c);
    }

    float acc0 = 0.0f, acc1 = 0.0f, acc2 = 0.0f, acc3 = 0.0f;
    #pragma unroll
    for (int u = 0; u < 16; ++u) {
        const float4 x4 = xs[u];
        const float4 p4 = ps[u];
        const float w0 = ((p4.x > 0.5f) && (x4.x >= gt)) ? fmaf(1.012f, x4.x, 0.012f) : x4.x;
        const float w1 = ((p4.y > 0.5f) && (x4.y >= gt)) ? fmaf(1.012f, x4.y, 0.012f) : x4.y;
        const float w2 = ((p4.z > 0.5f) && (x4.z >= gt)) ? fmaf(1.012f, x4.z, 0.012f) : x4.z;
        const float w3 = ((p4.w > 0.5f) && (x4.w >= gt)) ? fmaf(1.012f, x4.w, 0.012f) : x4.w;
        acc0 += __builtin_amdgcn_exp2f(fmaf(w0, k16l2e, nshift2));
        acc1 += __builtin_amdgcn_exp2f(fmaf(w1, k16l2e, nshift2));
        acc2 += __builtin_amdgcn_exp2f(fmaf(w2, k16l2e, nshift2));
        acc3 += __builtin_amdgcn_exp2f(fmaf(w3, k16l2e, nshift2));
    }

    float s = (acc0 + acc1) + (acc2 + acc3);

    // wave-64 shuffle reduce (sum)
    #pragma unroll
    for (int off = 32; off > 0; off >>= 1)
        s += __shfl_down(s, off);

    __shared__ float red_s[4];
    const int wave = tid >> 6;
    const int lane = tid & 63;
    if (lane == 0) red_s[wave] = s;
    __syncthreads();

    if (tid == 0) {
        float total = (red_s[0] + red_s[1]) + (red_s[2] + red_s[3]);
        // Exact correction for the target slot: the loop computed it with the
        // generic formula (x[t]==gt so x>=gt is true); replace with wt.
        const float w_wrong = (pos_t > 0.5f) ? fmaf(1.012f, gt, 0.012f) : gt;
        total += __builtin_amdgcn_exp2f(fmaf(wt,      k16l2e, nshift2))
               - __builtin_amdgcn_exp2f(fmaf(w_wrong, k16l2e, nshift2));
        const float loss_row = (__logf(total) + shift) - out_t;
        if (USE_ATOMIC) {
            atomicAdd(sink, loss_row * (1.0f / (float)B_));
        } else {
            sink[row] = loss_row;              // plain coalesced store
        }
    }
}

// Fold 4096 per-row losses into the mean. One 256-thr block; ~3us.
__global__ __launch_bounds__(256, 1) void coscam_reduce_kernel(
    const float* __restrict__ partial,
    float*       __restrict__ out)
{
    const int tid = threadIdx.x;
    float s = 0.0f;
    #pragma unroll
    for (int u = 0; u < 16; ++u)
        s += partial[u * 256 + tid];

    #pragma unroll
    for (int off = 32; off > 0; off >>= 1)
        s += __shfl_down(s, off);

    __shared__ float red_s[4];
    if ((tid & 63) == 0) red_s[tid >> 6] = s;
    __syncthreads();

    if (tid == 0) {
        float total = (red_s[0] + red_s[1]) + (red_s[2] + red_s[3]);
        out[0] = total * (1.0f / (float)B_);   // overwrites poison; no memset needed
    }
}

extern "C" void kernel_launch(void* const* d_in, const int* in_sizes, int n_in,
                              void* d_out, int out_size, void* d_ws, size_t ws_size,
                              hipStream_t stream) {
    const float* inputs   = (const float*)d_in[0];
    const int*   targets  = (const int*)  d_in[1];
    // d_in[2] = mask (unused by the reference)
    const float* pos_mask = (const float*)d_in[3];
    float* out = (float*)d_out;

    if (d_ws != nullptr && ws_size >= (size_t)B_ * sizeof(float)) {
        // Fast path: per-row partials in workspace + 1-block reduce.
        float* partial = (float*)d_ws;
        coscam_loss_kernel<false><<<dim3(B_), dim3(256), 0, stream>>>(
            inputs, targets, pos_mask, partial);
        coscam_reduce_kernel<<<dim3(1), dim3(256), 0, stream>>>(partial, out);
    } else {
        // Fallback: R4 harness-verified path (memset + same-address atomics).
        (void)hipMemsetAsync(out, 0, sizeof(float), stream);
        coscam_loss_kernel<true><<<dim3(B_), dim3(256), 0, stream>>>(
            inputs, targets, pos_mask, out);
    }
}